// Round 3
// baseline (1944.649 us; speedup 1.0000x reference)
//
#include <hip/hip_runtime.h>
#include <hip/hip_bf16.h>
#include <math.h>

#define B_ 8
#define S_ 1024
#define D_ 1024
#define TS_ 6144
#define NSLOT_ 128
#define LSTART_ 384
#define NEGV (-1e30f)

using bf16 = __hip_bfloat16;
typedef __attribute__((ext_vector_type(8))) short short8;
typedef __attribute__((ext_vector_type(4))) float f32x4;

__device__ __forceinline__ float b2f(bf16 x){ return __bfloat162float(x); }
__device__ __forceinline__ bf16 f2b(float x){ return __float2bfloat16(x); }

__device__ __forceinline__ float wredmax(float x){
  #pragma unroll
  for (int o=32;o;o>>=1) x = fmaxf(x, __shfl_xor(x, o, 64));
  return x;
}
__device__ __forceinline__ float wredsum(float x){
  #pragma unroll
  for (int o=32;o;o>>=1) x += __shfl_xor(x, o, 64);
  return x;
}

// ---------------- f32 -> bf16 convert ----------------
__global__ __launch_bounds__(256)
void cvt_k(const float* __restrict__ src, bf16* __restrict__ dst, long n)
{
  long i = ((long)blockIdx.x * 256 + threadIdx.x) * 4;
  if (i >= n) return;
  float4 v = *(const float4*)(src + i);
  dst[i+0] = f2b(v.x); dst[i+1] = f2b(v.y);
  dst[i+2] = f2b(v.z); dst[i+3] = f2b(v.w);
}

// ---------------- Generic strided-batched GEMM-TN: C = alpha*A@W^T + bias ----------------
// A: [M,K] lda (bf16), W: [N,K] ldb (bf16), C: [M,N] ldc (bf16).
// bias (f32, len N at this offset) nullable; rowscale (f32, idx z*M+m) nullable; act 1 = exact gelu.
__global__ __launch_bounds__(256)
void gemm_tn(const bf16* __restrict__ A, const bf16* __restrict__ W, bf16* __restrict__ C,
             const float* __restrict__ bias, const float* __restrict__ rowscale,
             int M, int N, int K, int lda, int ldb, int ldc, int nH,
             long sAb, long sAh, long sBb, long sBh, long sCb, long sCh,
             float alpha, int act)
{
  int z = blockIdx.z;
  int bb = z / nH, hh = z - bb * nH;
  A += bb * sAb + hh * sAh;
  W += bb * sBb + hh * sBh;
  C += bb * sCb + hh * sCh;

  __shared__ __align__(16) bf16 As[128*32];
  __shared__ __align__(16) bf16 Bs[128*32];

  int tid = threadIdx.x;
  int lane = tid & 63;
  int wid = tid >> 6;
  int wm = wid >> 1, wn = wid & 1;

  long m0 = (long)blockIdx.x * 128;
  long n0 = (long)blockIdx.y * 128;

  int srow = tid >> 2;        // 0..63
  int sk = (tid & 3) << 3;    // 0,8,16,24

  const bf16* ap = A + (m0 + srow) * (long)lda + sk;
  const bf16* bp = W + (n0 + srow) * (long)ldb + sk;
  long a64 = 64L * lda, b64 = 64L * ldb;

  f32x4 zero = {0.f, 0.f, 0.f, 0.f};
  f32x4 acc[4][4];
  #pragma unroll
  for (int i=0;i<4;i++)
    #pragma unroll
    for (int j=0;j<4;j++) acc[i][j] = zero;

  short8 ra0 = *(const short8*)ap;
  short8 ra1 = *(const short8*)(ap + a64);
  short8 rb0 = *(const short8*)bp;
  short8 rb1 = *(const short8*)(bp + b64);

  int lrow = lane & 15;
  int lk = (lane >> 4) << 3;
  int nk = K >> 5;

  for (int kt = 0; kt < nk; ++kt) {
    __syncthreads();
    *(short8*)(As + srow*32 + sk) = ra0;
    *(short8*)(As + (srow+64)*32 + sk) = ra1;
    *(short8*)(Bs + srow*32 + sk) = rb0;
    *(short8*)(Bs + (srow+64)*32 + sk) = rb1;
    __syncthreads();
    if (kt + 1 < nk) {
      ap += 32; bp += 32;
      ra0 = *(const short8*)ap;
      ra1 = *(const short8*)(ap + a64);
      rb0 = *(const short8*)bp;
      rb1 = *(const short8*)(bp + b64);
    }
    short8 af[4], bfr[4];
    #pragma unroll
    for (int i=0;i<4;i++) {
      af[i]  = *(const short8*)(As + (wm*64 + i*16 + lrow)*32 + lk);
      bfr[i] = *(const short8*)(Bs + (wn*64 + i*16 + lrow)*32 + lk);
    }
    #pragma unroll
    for (int i=0;i<4;i++)
      #pragma unroll
      for (int j=0;j<4;j++)
        acc[i][j] = __builtin_amdgcn_mfma_f32_16x16x32_bf16(af[i], bfr[j], acc[i][j], 0, 0, 0);
  }

  long crow0 = m0 + wm*64 + ((lane >> 4) << 2);
  long ccol0 = n0 + wn*64 + lrow;
  #pragma unroll
  for (int j=0;j<4;j++) {
    long nc = ccol0 + j*16;
    float bv = bias ? bias[nc] : 0.f;
    #pragma unroll
    for (int i=0;i<4;i++) {
      #pragma unroll
      for (int r=0;r<4;r++) {
        long mr = crow0 + i*16 + r;
        float v = acc[i][j][r] * alpha + bv;
        if (act == 1) v = 0.5f * v * (1.f + erff(v * 0.70710678118654752f));
        if (rowscale) v *= rowscale[(long)z * M + mr];
        C[mr * ldc + nc] = f2b(v);
      }
    }
  }
}

// ---------------- cache softmax: mask + slot-bias + softmax over TS=6144, in-place ----------------
__global__ __launch_bounds__(256)
void softmax_cache(bf16* __restrict__ sc, const int* __restrict__ mask,
                   const int* __restrict__ wc, const float* __restrict__ probs)
{
  long row = blockIdx.x;               // b*S + s
  int b = (int)(row >> 10);
  bf16* sp = sc + row * TS_;
  const float* pp = probs + row * NSLOT_;
  const int* mp = mask + (long)b * TS_;
  const int* wp = wc + (long)b * TS_;
  int tid = threadIdx.x;
  float v[24];
  float mx = -3.0e38f;
  #pragma unroll
  for (int it=0; it<24; ++it) {
    int t = tid + (it << 8);
    float s = b2f(sp[t]);
    if (mp[t] != 0 || wp[t] == 0) s = NEGV;
    int d = t - LSTART_;
    if ((unsigned)d < (unsigned)NSLOT_) s += 5.f * pp[d];
    v[it] = s;
    mx = fmaxf(mx, s);
  }
  __shared__ float red[4];
  mx = wredmax(mx);
  if ((tid & 63) == 0) red[tid>>6] = mx;
  __syncthreads();
  mx = fmaxf(fmaxf(red[0],red[1]), fmaxf(red[2],red[3]));
  float sum = 0.f;
  #pragma unroll
  for (int it=0; it<24; ++it) { v[it] = expf(v[it]-mx); sum += v[it]; }
  __syncthreads();
  sum = wredsum(sum);
  if ((tid & 63) == 0) red[tid>>6] = sum;
  __syncthreads();
  sum = red[0]+red[1]+red[2]+red[3];
  float inv = 1.f / sum;
  #pragma unroll
  for (int it=0; it<24; ++it) sp[tid + (it<<8)] = f2b(v[it]*inv);
}

// ---------------- plain softmax over rows of 1024, in-place ----------------
__global__ __launch_bounds__(256)
void softmax1024(bf16* __restrict__ sc)
{
  long row = blockIdx.x;
  bf16* sp = sc + (row << 10);
  int tid = threadIdx.x;
  float v[4]; float mx = -3.0e38f;
  #pragma unroll
  for (int i=0;i<4;i++){ v[i] = b2f(sp[tid + (i<<8)]); mx = fmaxf(mx, v[i]); }
  __shared__ float red[4];
  mx = wredmax(mx);
  if ((tid&63)==0) red[tid>>6]=mx;
  __syncthreads();
  mx = fmaxf(fmaxf(red[0],red[1]), fmaxf(red[2],red[3]));
  float sum=0.f;
  #pragma unroll
  for (int i=0;i<4;i++){ v[i]=expf(v[i]-mx); sum+=v[i]; }
  __syncthreads();
  sum = wredsum(sum);
  if ((tid&63)==0) red[tid>>6]=sum;
  __syncthreads();
  float inv = 1.f/(red[0]+red[1]+red[2]+red[3]);
  #pragma unroll
  for (int i=0;i<4;i++) sp[tid+(i<<8)] = f2b(v[i]*inv);
}

// ---------------- LN(a + res) over rows of 1024; res from f32 or bf16; out bf16 or f32 ----------------
__global__ __launch_bounds__(256)
void ln_res(const bf16* __restrict__ a, const bf16* __restrict__ resb,
            const float* __restrict__ resf, const float* __restrict__ g,
            const float* __restrict__ be, bf16* __restrict__ ob, float* __restrict__ of)
{
  long row = blockIdx.x;
  const bf16* ap = a + (row << 10);
  int tid = threadIdx.x;
  float zv[4]; float s = 0.f;
  #pragma unroll
  for (int i=0;i<4;i++){
    int t = tid + (i<<8);
    float r = resf ? resf[(row<<10)+t] : b2f(resb[(row<<10)+t]);
    zv[i] = b2f(ap[t]) + r; s += zv[i];
  }
  __shared__ float red[4];
  s = wredsum(s);
  if ((tid&63)==0) red[tid>>6]=s;
  __syncthreads();
  float mean = (red[0]+red[1]+red[2]+red[3]) * (1.f/1024.f);
  float vs=0.f;
  #pragma unroll
  for (int i=0;i<4;i++){ float d = zv[i]-mean; vs += d*d; }
  __syncthreads();
  vs = wredsum(vs);
  if ((tid&63)==0) red[tid>>6]=vs;
  __syncthreads();
  float var = (red[0]+red[1]+red[2]+red[3]) * (1.f/1024.f);
  float rs = rsqrtf(var + 1e-5f);
  #pragma unroll
  for (int i=0;i<4;i++){
    int t = tid + (i<<8);
    float r = (zv[i]-mean)*rs*g[t] + be[t];
    if (of) of[(row<<10)+t] = r; else ob[(row<<10)+t] = f2b(r);
  }
}

// ---------------- transpose [R,C] -> [C,R] per (b,h) ----------------
__global__ __launch_bounds__(256)
void transp(const bf16* __restrict__ in, bf16* __restrict__ out,
            int ldin, int ldout, int nH, long sIb, long sIh, long sOb, long sOh)
{
  int z = blockIdx.z; int b = z / nH, h = z - b*nH;
  in += b*sIb + h*sIh; out += b*sOb + h*sOh;
  __shared__ bf16 t[32][33];
  int c0 = blockIdx.x << 5, r0 = blockIdx.y << 5;
  int tx = threadIdx.x & 31, ty = threadIdx.x >> 5;
  #pragma unroll
  for (int i=0;i<4;i++)
    t[ty + i*8][tx] = in[(long)(r0 + ty + i*8)*ldin + c0 + tx];
  __syncthreads();
  #pragma unroll
  for (int i=0;i<4;i++)
    out[(long)(c0 + ty + i*8)*ldout + r0 + tx] = t[tx][ty + i*8];
}

// ---------------- small elementwise kernels ----------------
__global__ __launch_bounds__(256)
void build_cwi_k(const float* __restrict__ cache, const float* __restrict__ lid,
                 const float* __restrict__ ages, bf16* __restrict__ cwi)
{
  long i = (long)blockIdx.x * 256 + threadIdx.x;
  if (i >= (long)B_*TS_*192) return;
  int f = (int)(i % 192); long bt = i / 192; int t = (int)(bt % TS_);
  float v;
  if (f < 128)       v = cache[bt*128 + f];
  else if (f < 160)  v = lid[(long)t*32 + (f-128)];
  else if (f == 160) v = ages[bt] * 0.01f;
  else               v = 0.f;
  cwi[i] = f2b(v);
}

__global__ __launch_bounds__(256)
void pad_w_k(const float* __restrict__ src, bf16* __restrict__ dst) // [128,161]f32 -> [128,192]bf16
{
  int i = blockIdx.x * 256 + threadIdx.x;
  if (i >= 128*192) return;
  int r = i / 192, c = i - r*192;
  dst[i] = f2b((c < 161) ? src[r*161 + c] : 0.f);
}

__global__ __launch_bounds__(256)
void decb2_k(const float* __restrict__ dec_w, const float* __restrict__ dec_b,
             const float* __restrict__ le, float* __restrict__ out)
{
  int n = blockIdx.x * 256 + threadIdx.x;
  if (n >= 1024) return;
  float s = dec_b[n];
  #pragma unroll
  for (int j=0;j<32;j++) s += dec_w[n*160 + 128 + j] * le[j];
  out[n] = s;
}

__global__ __launch_bounds__(256)
void concat2_k(const float* __restrict__ x, const bf16* __restrict__ xm, bf16* __restrict__ cat)
{
  long i = (long)blockIdx.x * 256 + threadIdx.x;
  if (i >= (long)8192*2048) return;
  long r = i >> 11; int c = (int)(i & 2047);
  cat[i] = (c < 1024) ? f2b(x[(r<<10) + c]) : xm[(r<<10) + c - 1024];
}

__global__ __launch_bounds__(256)
void blend_k(const bf16* __restrict__ gpre, const bf16* __restrict__ xm,
             const float* __restrict__ x, bf16* __restrict__ xf)
{
  long i = (long)blockIdx.x * 256 + threadIdx.x;
  if (i >= (long)8388608) return;
  float g = 1.f / (1.f + expf(-b2f(gpre[i])));
  xf[i] = f2b(g * b2f(xm[i]) + (1.f - g) * x[i]);
}

// ---------------- orchestration ----------------
extern "C" void kernel_launch(void* const* d_in, const int* in_sizes, int n_in,
                              void* d_out, int out_size, void* d_ws, size_t ws_size,
                              hipStream_t stream)
{
  (void)in_sizes; (void)n_in; (void)out_size; (void)ws_size;
  const float* x     = (const float*)d_in[0];
  const float* cache = (const float*)d_in[1];
  const float* lid   = (const float*)d_in[2];
  const float* ages  = (const float*)d_in[3];
  const float* rgate = (const float*)d_in[4];
  const float* rprob = (const float*)d_in[5];
  const float* lemb  = (const float*)d_in[6];
  const float* cq_w  = (const float*)d_in[7];
  const float* cq_b  = (const float*)d_in[8];
  const float* ck_w  = (const float*)d_in[9];
  const float* ck_b  = (const float*)d_in[10];
  const float* cv_w  = (const float*)d_in[11];
  const float* cv_b  = (const float*)d_in[12];
  const float* dec_w = (const float*)d_in[13];
  const float* dec_b = (const float*)d_in[14];
  const float* cwin  = (const float*)d_in[15];
  const float* cbin  = (const float*)d_in[16];
  const float* cwout = (const float*)d_in[17];
  const float* cbout = (const float*)d_in[18];
  const float* ng    = (const float*)d_in[19];
  const float* nbv   = (const float*)d_in[20];
  const float* gw    = (const float*)d_in[21];
  const float* gb    = (const float*)d_in[22];
  const float* swin  = (const float*)d_in[23];
  const float* sbin  = (const float*)d_in[24];
  const float* swout = (const float*)d_in[25];
  const float* sbout = (const float*)d_in[26];
  const float* n1g   = (const float*)d_in[27];
  const float* n1b   = (const float*)d_in[28];
  const float* f1w   = (const float*)d_in[29];
  const float* f1b   = (const float*)d_in[30];
  const float* f2w   = (const float*)d_in[31];
  const float* f2bv  = (const float*)d_in[32];
  const float* n2g   = (const float*)d_in[33];
  const float* n2b   = (const float*)d_in[34];
  const int*  cmask = (const int*)d_in[35];
  const int*  wcnt  = (const int*)d_in[36];
  float* out = (float*)d_out;

  bf16* ws = (bf16*)d_ws;
  const long MB8 = 8388608;
  // ---- persistent bf16 copies ----
  bf16* xb     = ws + 0;           // 8,388,608
  bf16* cq_wb  = ws + 8388608;     // 131,072
  bf16* dec_wb = ws + 8519680;     // 163,840
  bf16* cwinb  = ws + 8683520;     // 3,145,728
  bf16* cwoutb = ws + 11829248;    // 1,048,576
  bf16* gwb    = ws + 12877824;    // 2,097,152
  bf16* swinb  = ws + 14974976;    // 3,145,728
  bf16* swoutb = ws + 18120704;    // 1,048,576
  bf16* f1wb   = ws + 19169280;    // 4,194,304
  bf16* f2wb   = ws + 23363584;    // 4,194,304
  bf16* ckpb   = ws + 27557888;    // 24,576
  bf16* cvpb   = ws + 27582464;    // 24,576
  float* db2f  = (float*)(ws + 27607040);  // f32[1024] = 2048 bf16 slots
  // ---- dynamic region ----
  const long F    = 27609088;
  const long BIGC = F + 25165824;  // ends F+75,497,472 = 103,106,560 elems (206.2 MB)
  bf16* cwi  = ws + F;             // ph1 [49152,192]
  bf16* vTc  = ws + F;             // ph1 (cwi dead)
  bf16* raw  = ws + F + 6291456;
  bf16* ctx  = ws + F + 7340032;
  bf16* kc   = ws + F + 9437184;
  bf16* vc   = ws + F + 15728640;
  bf16* qc   = ws + F + 22020096;
  bf16* xfb  = ws + F + 16777216;  // ph3-4 (vc/qc dead)
  bf16* qs   = ws + F;             // ph4
  bf16* ks   = ws + F + 8388608;   // ph4
  bf16* bigC = ws + BIGC;          // ph1 cache scores [8,1024,6144] = 6*MB8
  bf16* sc    = ws + BIGC;             // per-b scores [8 heads,1024,1024]
  bf16* qx    = ws + BIGC + 1*MB8;
  bf16* kcx   = ws + BIGC + 2*MB8;
  bf16* vcx   = ws + BIGC + 3*MB8;
  bf16* vT2   = ws + BIGC + 4*MB8;     // single-batch [8h][128,1024]
  bf16* obuf  = ws + BIGC + 5*MB8;
  bf16* aout  = ws + BIGC + 4*MB8;     // after b-loop (vT2 dead)
  bf16* xmb   = ws + BIGC + 3*MB8;     // after vcx dead
  bf16* cat2  = ws + BIGC;             // ph3 [8192,2048] = 2*MB8
  bf16* gpre  = ws + BIGC + 2*MB8;     // ph3
  bf16* vbuf  = ws + BIGC + 5*MB8;     // ph4 v-proj out
  bf16* vT24  = ws + BIGC + 1*MB8;     // ph4 per-b
  bf16* obuf4 = ws + BIGC + 2*MB8;     // ph4
  bf16* aout4 = ws + BIGC + 3*MB8;     // ph4
  bf16* xf2   = ws + BIGC + 4*MB8;     // ph4-5
  bf16* hbuf  = ws + BIGC;             // ph5 [8192,4096] = 4*MB8
  bf16* fout  = ws + BIGC + 5*MB8;     // ph5 (vbuf dead)

  const float ISQ = 0.08838834764831845f; // 1/sqrt(128)

  auto gemm = [&](const bf16* A, const bf16* W, bf16* C, const float* bias, const float* rs,
                  int M, int N, int K, int lda, int ldb, int ldc, int batch, int nH,
                  long sAb, long sAh, long sBb, long sBh, long sCb, long sCh,
                  float alpha, int act) {
    dim3 g(M/128, N/128, batch);
    gemm_tn<<<g, dim3(256), 0, stream>>>(A, W, C, bias, rs, M, N, K, lda, ldb, ldc, nH,
                                         sAb, sAh, sBb, sBh, sCb, sCh, alpha, act);
  };
  auto cvt = [&](const float* s, bf16* d, long n) {
    cvt_k<<<dim3((unsigned)(n/1024)), dim3(256), 0, stream>>>(s, d, n);
  };

  // ======== Phase 0: dtype conversion ========
  cvt(x, xb, 8388608);
  cvt(cq_w, cq_wb, 131072);
  cvt(dec_w, dec_wb, 163840);
  cvt(cwin, cwinb, 3145728);
  cvt(cwout, cwoutb, 1048576);
  cvt(gw, gwb, 2097152);
  cvt(swin, swinb, 3145728);
  cvt(swout, swoutb, 1048576);
  cvt(f1w, f1wb, 4194304);
  cvt(f2w, f2wb, 4194304);
  pad_w_k<<<dim3(96), dim3(256), 0, stream>>>(ck_w, ckpb);
  pad_w_k<<<dim3(96), dim3(256), 0, stream>>>(cv_w, cvpb);
  decb2_k<<<dim3(4), dim3(256), 0, stream>>>(dec_w, dec_b, lemb, db2f);
  build_cwi_k<<<dim3(36864), dim3(256), 0, stream>>>(cache, lid, ages, cwi);

  // ======== Phase 1: READ (cache attention) ========
  gemm(xb,  cq_wb, qc, cq_b, nullptr, 8192, 128, 1024, 1024, 1024, 128, 1,1, 0,0,0,0,0,0, 1.f, 0);
  gemm(cwi, ckpb,  kc, ck_b, nullptr, 49152, 128, 192, 192, 192, 128, 1,1, 0,0,0,0,0,0, 1.f, 0);
  gemm(cwi, cvpb,  vc, cv_b, nullptr, 49152, 128, 192, 192, 192, 128, 1,1, 0,0,0,0,0,0, 1.f, 0);
  // vc [B*6144,128] -> vTc [B][128,6144]   (cwi dead)
  transp<<<dim3(4,192,8), dim3(256), 0, stream>>>(vc, vTc, 128, 6144, 1,
      (long)6144*128, 0L, (long)128*6144, 0L);
  gemm(qc, kc, bigC, nullptr, nullptr, 1024, 6144, 128, 128, 128, 6144, 8, 1,
       (long)1024*128, 0, (long)6144*128, 0, (long)1024*6144, 0, ISQ, 0);
  softmax_cache<<<dim3(8192), dim3(256), 0, stream>>>(bigC, cmask, wcnt, rprob);
  gemm(bigC, vTc, raw, nullptr, nullptr, 1024, 128, 6144, 6144, 6144, 128, 8, 1,
       (long)1024*6144, 0, (long)128*6144, 0, (long)1024*128, 0, 1.f, 0);
  gemm(raw, dec_wb, ctx, db2f, rgate, 8192, 1024, 128, 128, 160, 1024, 1,1, 0,0,0,0,0,0, 1.f, 0);

  // ======== Phase 2: cross MHA (q from x, k/v from ctx) ========
  gemm(xb,  cwinb,               qx,  cbin,      nullptr, 8192, 1024, 1024, 1024,1024,1024, 1,1, 0,0,0,0,0,0, 1.f, 0);
  gemm(ctx, cwinb + 1024*1024,   kcx, cbin+1024, nullptr, 8192, 1024, 1024, 1024,1024,1024, 1,1, 0,0,0,0,0,0, 1.f, 0);
  gemm(ctx, cwinb + 2048*1024,   vcx, cbin+2048, nullptr, 8192, 1024, 1024, 1024,1024,1024, 1,1, 0,0,0,0,0,0, 1.f, 0);
  for (int b = 0; b < 8; ++b) {
    transp<<<dim3(4,32,8), dim3(256), 0, stream>>>(vcx + b*(long)1048576, vT2, 1024, 1024, 8,
        0L, 128L, 0L, 131072L);
    gemm(qx + b*(long)1048576, kcx + b*(long)1048576, sc, nullptr, nullptr,
         1024, 1024, 128, 1024, 1024, 1024, 8, 8,
         0, 128, 0, 128, 0, (long)1048576, ISQ, 0);
    softmax1024<<<dim3(8192), dim3(256), 0, stream>>>(sc);
    gemm(sc, vT2, obuf + b*(long)1048576, nullptr, nullptr,
         1024, 128, 1024, 1024, 1024, 1024, 8, 8,
         0, (long)1048576, 0, (long)131072, 0, 128, 1.f, 0);
  }
  gemm(obuf, cwoutb, aout, cbout, nullptr, 8192, 1024, 1024, 1024,1024,1024, 1,1, 0,0,0,0,0,0, 1.f, 0);
  ln_res<<<dim3(8192), dim3(256), 0, stream>>>(aout, nullptr, x, ng, nbv, xmb, nullptr);

  // ======== Phase 3: gated fusion ========
  concat2_k<<<dim3(65536), dim3(256), 0, stream>>>(x, xmb, cat2);
  gemm(cat2, gwb, gpre, gb, nullptr, 8192, 1024, 2048, 2048, 2048, 1024, 1,1, 0,0,0,0,0,0, 1.f, 0);
  blend_k<<<dim3(32768), dim3(256), 0, stream>>>(gpre, xmb, x, xfb);

  // ======== Phase 4: self MHA on xf ========
  gemm(xfb, swinb,               qs,   sbin,      nullptr, 8192, 1024, 1024, 1024,1024,1024, 1,1, 0,0,0,0,0,0, 1.f, 0);
  gemm(xfb, swinb + 1024*1024,   ks,   sbin+1024, nullptr, 8192, 1024, 1024, 1024,1024,1024, 1,1, 0,0,0,0,0,0, 1.f, 0);
  gemm(xfb, swinb + 2048*1024,   vbuf, sbin+2048, nullptr, 8192, 1024, 1024, 1024,1024,1024, 1,1, 0,0,0,0,0,0, 1.f, 0);
  for (int b = 0; b < 8; ++b) {
    transp<<<dim3(4,32,8), dim3(256), 0, stream>>>(vbuf + b*(long)1048576, vT24, 1024, 1024, 8,
        0L, 128L, 0L, 131072L);
    gemm(qs + b*(long)1048576, ks + b*(long)1048576, sc, nullptr, nullptr,
         1024, 1024, 128, 1024, 1024, 1024, 8, 8,
         0, 128, 0, 128, 0, (long)1048576, ISQ, 0);
    softmax1024<<<dim3(8192), dim3(256), 0, stream>>>(sc);
    gemm(sc, vT24, obuf4 + b*(long)1048576, nullptr, nullptr,
         1024, 128, 1024, 1024, 1024, 1024, 8, 8,
         0, (long)1048576, 0, (long)131072, 0, 128, 1.f, 0);
  }
  gemm(obuf4, swoutb, aout4, sbout, nullptr, 8192, 1024, 1024, 1024,1024,1024, 1,1, 0,0,0,0,0,0, 1.f, 0);
  ln_res<<<dim3(8192), dim3(256), 0, stream>>>(aout4, xfb, nullptr, n1g, n1b, xf2, nullptr);

  // ======== Phase 5: FFN ========
  gemm(xf2, f1wb, hbuf, f1b, nullptr, 8192, 4096, 1024, 1024, 1024, 4096, 1,1, 0,0,0,0,0,0, 1.f, 1);
  gemm(hbuf, f2wb, fout, f2bv, nullptr, 8192, 1024, 4096, 4096, 4096, 1024, 1,1, 0,0,0,0,0,0, 1.f, 0);
  ln_res<<<dim3(8192), dim3(256), 0, stream>>>(fout, xf2, nullptr, n2g, n2b, nullptr, out);
}